// Round 22
// baseline (104.934 us; speedup 1.0000x reference)
//
#include <hip/hip_runtime.h>

typedef __attribute__((ext_vector_type(8))) short short8v;   // 8 bf16
typedef __attribute__((ext_vector_type(4))) short short4v;   // 4 bf16
typedef __attribute__((ext_vector_type(4))) float f32x4;

static __device__ __forceinline__ unsigned short f2bf(float f) {
  union { float f; unsigned u; } v;
  v.f = f;
  const unsigned u = v.u;
  return (unsigned short)((u + 0x7FFF + ((u >> 16) & 1)) >> 16);  // RNE
}
static __device__ __forceinline__ float bf2f(unsigned short s) {
  union { unsigned u; float f; } v;
  v.u = ((unsigned)s) << 16;
  return v.f;
}

// Intermediates xT,h1..h4 stored bf16 in [feature, B] layout (batch-last).

// ------ INIT: transpose x -> xT (blocks < nbTr) + all weight transforms ----
// Region layout for weights (bf16 shorts):
//  [0, N1)            Wm1[pos][o][32]  (w1: O=16,C=1, NPOS=169, K=9)
//  [N1, N1+N2)        Wm2[pos][o][160] (w2: O=32,C=16,NPOS=36, K=144)
//  [N1+N2, +N3)       Wm3[pos][o][288] (w3: O=64,C=32,NPOS=16, K=288)
//  [.., +N4)          Wbf[j*1024+k]    (fw1 bf16 copy)
__global__ __launch_bounds__(256) void k_init(
    const float* __restrict__ x, unsigned short* __restrict__ xT, int Bc,
    int nbTr, const float* __restrict__ w1, const float* __restrict__ w2,
    const float* __restrict__ w3, const float* __restrict__ fw1,
    unsigned short* __restrict__ Wm1, unsigned short* __restrict__ Wm2,
    unsigned short* __restrict__ Wm3, unsigned short* __restrict__ Wbf) {
  const int tid = threadIdx.x;
  if ((int)blockIdx.x < nbTr) {
    // ---- transpose tile: bx = bid % (Bc/32), by = bid / (Bc/32)
    __shared__ float t[32][33];
    const int nbx = Bc >> 5;
    const int bx = blockIdx.x % nbx, by = blockIdx.x / nbx;
    const int b0 = bx * 32, f0 = by * 32;
    const int tx = tid & 31, ty = tid >> 5;
    for (int r = ty; r < 32; r += 8) {
      const int f = f0 + tx;
      t[r][tx] = (f < 784) ? x[(size_t)(b0 + r) * 784 + f] : 0.f;
    }
    __syncthreads();
    for (int r = ty; r < 32; r += 8) {
      const int f = f0 + r;
      if (f < 784) xT[(size_t)f * Bc + b0 + tx] = f2bf(t[tx][r]);
    }
    return;
  }
  // ---- weight transforms, grid-stride over the tail blocks
  const int N1 = 169 * 16 * 32;      // 86528
  const int N2 = 36 * 32 * 160;      // 184320
  const int N3 = 16 * 64 * 288;      // 294912
  const int N4 = 512 * 1024;         // 524288
  const int total = N1 + N2 + N3 + N4;
  const int nw = gridDim.x - nbTr;
  for (int i = (blockIdx.x - nbTr) * 256 + tid; i * 8 < total; i += nw * 256) {
    const int base = i * 8;
#pragma unroll
    for (int u = 0; u < 8; ++u) {
      const int idx = base + u;
      if (idx < N1) {
        const int pos = idx >> 9, rem = idx & 511;
        const int o = rem >> 5, k = rem & 31;
        const float v = (k < 9) ? w1[((size_t)o * 169 + pos) * 9 + k] : 0.f;
        Wm1[idx] = f2bf(v);
      } else if (idx < N1 + N2) {
        const int j = idx - N1;
        const int pos = j / (32 * 160), rem = j - pos * (32 * 160);
        const int o = rem / 160, k = rem - o * 160;
        float v = 0.f;
        if (k < 144) {
          const int c = k / 9, kk = k - c * 9;
          v = w2[((size_t)(o * 16 + c) * 36 + pos) * 9 + kk];
        }
        Wm2[j] = f2bf(v);
      } else if (idx < N1 + N2 + N3) {
        const int j = idx - N1 - N2;
        const int pos = j / (64 * 288), rem = j - pos * (64 * 288);
        const int o = rem / 288, k = rem - o * 288;
        const int c = k / 9, kk = k - c * 9;
        Wm3[j] = f2bf(w3[((size_t)(o * 32 + c) * 16 + pos) * 9 + kk]);
      } else {
        const int j = idx - N1 - N2 - N3;
        Wbf[j] = f2bf(fw1[j]);
      }
    }
  }
}

// ---------------- LC layer via bf16 MFMA (bf16 in, bf16 out) ---------------
// SINGLE-buffered LDS; register prefetch across the two per-step barriers;
// cross-block TLP covers the rest (m114). BBT = batch-tile per block (256 for
// LC1 to amortize its per-block overhead: 1 K-step, tiny blocks).
// Wave split: O=64: 32o x 64b; O=32: 32o x 32b; O=16,BBT=256: 16o x 64b.
template <int O, int K, int NPOS, int HWIN, int WIN, int WOD, int STR,
          bool RELU, int BBT = 128>
__global__ __launch_bounds__(256) void k_lcm(
    const unsigned short* __restrict__ X, const unsigned short* __restrict__ Wm,
    const float* __restrict__ bias, unsigned short* __restrict__ out, int B) {
  constexpr int NSTEP = (K + 31) / 32;
  constexpr int Kpad = NSTEP * 32;
  constexpr int NBH = BBT / 128;  // staging halves
  constexpr int NJT = (O >= 32) ? 2 : 1;
  constexpr int NBT = (O == 64) ? 4 : ((BBT == 256) ? 4 : 2);
  __shared__ short Wl[O * 40];
  __shared__ short Xl[(BBT == 128) ? 5232 : 10480];
  __shared__ int rowtab[Kpad];
  const int tid = threadIdx.x;
  const int b0 = blockIdx.x * BBT;
  const int pos = blockIdx.y;
  const int ho = pos / WOD, wo = pos - ho * WOD;
  const int w = tid >> 6, l = tid & 63, m = l & 15, g = l >> 4;
  const int jw = (O == 64) ? (w & 1) * 32 : 0;
  const int boff = (O == 64) ? (w >> 1) * 64
                             : ((O == 32) ? w * 32 : w * (BBT / 4));

  for (int k = tid; k < Kpad; k += 256) {
    int r = 0;
    if (k < K) {
      const int c = k / 9, kk = k - c * 9;
      const int kh = kk / 3, kw = kk - kh * 3;
      r = c * HWIN + (ho * STR + kh) * WIN + (wo * STR + kw);
    }
    rowtab[k] = r;
  }
  __syncthreads();

  const unsigned short* wsrc = Wm + (size_t)pos * O * Kpad;
  const int wjj = tid >> 2, wko = (tid & 3) * 8;
  const bool wact = tid < O * 4;
  const int kp = tid >> 4, boct = (tid & 15) * 8;

  f32x4 acc[NJT][NBT];
#pragma unroll
  for (int jt = 0; jt < NJT; ++jt)
#pragma unroll
    for (int bt = 0; bt < NBT; ++bt) acc[jt][bt] = (f32x4){0.f, 0.f, 0.f, 0.f};

  short8v wreg, xav[NBH], xbv[NBH];
  bool z0, z1;

  // ---- prologue: load + stage step 0
  if (wact) wreg = *(const short8v*)&wsrc[(size_t)wjj * Kpad + wko];
  {
    const int k0 = 2 * kp;
    z0 = k0 >= K;
    z1 = k0 + 1 >= K;
#pragma unroll
    for (int bh = 0; bh < NBH; ++bh) {
      if (!z0)
        xav[bh] = *(const short8v*)(X + (size_t)rowtab[k0] * B + b0 +
                                    bh * 128 + boct);
      if (!z1)
        xbv[bh] = *(const short8v*)(X + (size_t)rowtab[k0 + 1] * B + b0 +
                                    bh * 128 + boct);
    }
  }
  if (wact) *(short8v*)&Wl[wjj * 40 + wko] = wreg;
  {
    unsigned* xl = (unsigned*)&Xl[0];
#pragma unroll
    for (int bh = 0; bh < NBH; ++bh)
#pragma unroll
      for (int i = 0; i < 8; ++i) {
        const int b = bh * 128 + boct + i;
        const unsigned lo = z0 ? 0u : (unsigned)(unsigned short)xav[bh][i];
        const unsigned hi = z1 ? 0u : (unsigned)(unsigned short)xbv[bh][i];
        xl[b * 20 + (b >> 3) * 4 + kp] = lo | (hi << 16);
      }
  }
  __syncthreads();

  for (int t = 0; t < NSTEP; ++t) {
    if (t < NSTEP - 1) {  // issue next step's loads into registers
      const int kc = (t + 1) * 32;
      if (wact) wreg = *(const short8v*)&wsrc[(size_t)wjj * Kpad + kc + wko];
      const int k0 = kc + 2 * kp;
      z0 = k0 >= K;
      z1 = k0 + 1 >= K;
#pragma unroll
      for (int bh = 0; bh < NBH; ++bh) {
        if (!z0)
          xav[bh] = *(const short8v*)(X + (size_t)rowtab[k0] * B + b0 +
                                      bh * 128 + boct);
        if (!z1)
          xbv[bh] = *(const short8v*)(X + (size_t)rowtab[k0 + 1] * B + b0 +
                                      bh * 128 + boct);
      }
    }
    {
      short8v aw[NJT], bx[NBT];
#pragma unroll
      for (int jt = 0; jt < NJT; ++jt)
        aw[jt] = *(const short8v*)&Wl[(jw + jt * 16 + m) * 40 + g * 8];
#pragma unroll
      for (int bt = 0; bt < NBT; ++bt) {
        const int b = boff + bt * 16 + m;
        bx[bt] = *(const short8v*)&Xl[b * 40 + (b >> 3) * 8 + g * 8];
      }
#pragma unroll
      for (int jt = 0; jt < NJT; ++jt)
#pragma unroll
        for (int bt = 0; bt < NBT; ++bt)
          acc[jt][bt] = __builtin_amdgcn_mfma_f32_16x16x32_bf16(
              aw[jt], bx[bt], acc[jt][bt], 0, 0, 0);
    }
    if (t < NSTEP - 1) {
      __syncthreads();  // all waves done reading Xl/Wl
      if (wact) *(short8v*)&Wl[wjj * 40 + wko] = wreg;
      unsigned* xl = (unsigned*)&Xl[0];
#pragma unroll
      for (int bh = 0; bh < NBH; ++bh)
#pragma unroll
        for (int i = 0; i < 8; ++i) {
          const int b = bh * 128 + boct + i;
          const unsigned lo = z0 ? 0u : (unsigned)(unsigned short)xav[bh][i];
          const unsigned hi = z1 ? 0u : (unsigned)(unsigned short)xbv[bh][i];
          xl[b * 20 + (b >> 3) * 4 + kp] = lo | (hi << 16);
        }
      __syncthreads();  // writes visible before next MFMA
    }
  }

#pragma unroll
  for (int jt = 0; jt < NJT; ++jt)
#pragma unroll
    for (int r = 0; r < 4; ++r) {
      const int o = jw + jt * 16 + g * 4 + r;
      const int f = o * NPOS + pos;
      const float bz = bias[f];
#pragma unroll
      for (int bt = 0; bt < NBT; ++bt) {
        float v = acc[jt][bt][r] + bz;
        if (RELU) v = fmaxf(v, 0.f);
        out[(size_t)f * B + b0 + boff + bt * 16 + m] = f2bf(v);
      }
    }
}

// ---------------- FC1 via bf16 MFMA, 64-b tiles (2 blocks/CU) --------------
__global__ __launch_bounds__(256) void k_fc1m(
    const unsigned short* __restrict__ X,
    const unsigned short* __restrict__ Wbf, const float* __restrict__ fb1,
    unsigned short* __restrict__ out, int B) {
  __shared__ short Wl[2][5120];   // 128 j x 40 shorts
  __shared__ short Xl[2][2608];   // 64 b x 40 + monotone stagger
  const int tid = threadIdx.x;
  const int b0 = blockIdx.x * 64, j0 = blockIdx.y * 128;
  const int w = tid >> 6, l = tid & 63, m = l & 15, g = l >> 4;

  const int wj = tid >> 1, wkh = (tid & 1) * 16;
  const unsigned short* wsrc = Wbf + (size_t)(j0 + wj) * 1024 + wkh;
  const int kp = tid >> 4, bq = (tid & 15) * 4;  // k-pair, 4 b per thread
  const unsigned short* xsrc = X + (size_t)(2 * kp) * B + b0 + bq;

  f32x4 acc[2][4];
#pragma unroll
  for (int jt = 0; jt < 2; ++jt)
#pragma unroll
    for (int bt = 0; bt < 4; ++bt) acc[jt][bt] = (f32x4){0.f, 0.f, 0.f, 0.f};

  short8v wreg0, wreg1;
  short4v xa, xb;

  wreg0 = *(const short8v*)(wsrc);
  wreg1 = *(const short8v*)(wsrc + 8);
  xa = *(const short4v*)(xsrc);
  xb = *(const short4v*)(xsrc + B);

  {
    *(short8v*)&Wl[0][wj * 40 + wkh] = wreg0;
    *(short8v*)&Wl[0][wj * 40 + wkh + 8] = wreg1;
    unsigned* xl = (unsigned*)&Xl[0][0];
#pragma unroll
    for (int i = 0; i < 4; ++i) {
      const int b = bq + i;
      xl[b * 20 + (b >> 3) * 4 + kp] = (unsigned)(unsigned short)xa[i] |
                                       ((unsigned)(unsigned short)xb[i] << 16);
    }
  }
  __syncthreads();

  for (int t = 0; t < 32; ++t) {
    const int cur = t & 1;
    if (t < 31) {
      const unsigned short* wp = wsrc + (t + 1) * 32;
      wreg0 = *(const short8v*)(wp);
      wreg1 = *(const short8v*)(wp + 8);
      const unsigned short* xp = xsrc + (size_t)(t + 1) * 32 * B;
      xa = *(const short4v*)(xp);
      xb = *(const short4v*)(xp + B);
    }
    {
      short8v aw[2], bx[4];
#pragma unroll
      for (int jt = 0; jt < 2; ++jt)
        aw[jt] = *(const short8v*)&Wl[cur][(w * 32 + jt * 16 + m) * 40 + g * 8];
#pragma unroll
      for (int bt = 0; bt < 4; ++bt) {
        const int b = bt * 16 + m;
        bx[bt] = *(const short8v*)&Xl[cur][b * 40 + (b >> 3) * 8 + g * 8];
      }
#pragma unroll
      for (int jt = 0; jt < 2; ++jt)
#pragma unroll
        for (int bt = 0; bt < 4; ++bt)
          acc[jt][bt] = __builtin_amdgcn_mfma_f32_16x16x32_bf16(
              aw[jt], bx[bt], acc[jt][bt], 0, 0, 0);
    }
    if (t < 31) {
      const int nxt = cur ^ 1;
      *(short8v*)&Wl[nxt][wj * 40 + wkh] = wreg0;
      *(short8v*)&Wl[nxt][wj * 40 + wkh + 8] = wreg1;
      unsigned* xl = (unsigned*)&Xl[nxt][0];
#pragma unroll
      for (int i = 0; i < 4; ++i) {
        const int b = bq + i;
        xl[b * 20 + (b >> 3) * 4 + kp] =
            (unsigned)(unsigned short)xa[i] |
            ((unsigned)(unsigned short)xb[i] << 16);
      }
    }
    __syncthreads();
  }

#pragma unroll
  for (int jt = 0; jt < 2; ++jt)
#pragma unroll
    for (int r = 0; r < 4; ++r) {
      const int j = j0 + w * 32 + jt * 16 + g * 4 + r;
      const float bj = fb1[j];
#pragma unroll
      for (int bt = 0; bt < 4; ++bt)
        out[(size_t)j * B + b0 + bt * 16 + m] =
            f2bf(fmaxf(acc[jt][bt][r] + bj, 0.f));
    }
}

// ---------------- FC2: out[b,10] = fw2[10,512] @ h4[512,B] + fb2 -----------
__global__ __launch_bounds__(512) void k_fc2(
    const unsigned short* __restrict__ in, const float* __restrict__ fw2,
    const float* __restrict__ fb2, float* __restrict__ out, int B, int b0) {
  __shared__ float red[8][10][64];
  const int tx = threadIdx.x;
  const int b = blockIdx.x * 64 + tx;
  const int tyu = threadIdx.y;
  float acc[10];
#pragma unroll
  for (int i = 0; i < 10; ++i) acc[i] = 0.f;
  for (int kk = 0; kk < 64; ++kk) {
    const int k = tyu * 64 + kk;
    const float v = bf2f(in[(size_t)k * B + b]);
#pragma unroll
    for (int i = 0; i < 10; ++i) acc[i] = fmaf(v, fw2[i * 512 + k], acc[i]);
  }
#pragma unroll
  for (int i = 0; i < 10; ++i) red[tyu][i][tx] = acc[i];
  __syncthreads();
  if (tyu == 0) {
#pragma unroll
    for (int i = 0; i < 10; ++i) {
      float s = fb2[i];
#pragma unroll
      for (int q = 0; q < 8; ++q) s += red[q][i][tx];
      out[(size_t)(b0 + b) * 10 + i] = s;
    }
  }
}

extern "C" void kernel_launch(void* const* d_in, const int* in_sizes, int n_in,
                              void* d_out, int out_size, void* d_ws,
                              size_t ws_size, hipStream_t stream) {
  const float* x   = (const float*)d_in[0];
  const float* w1  = (const float*)d_in[1];
  const float* b1  = (const float*)d_in[2];
  const float* w2  = (const float*)d_in[3];
  const float* b2  = (const float*)d_in[4];
  const float* w3  = (const float*)d_in[5];
  const float* b3  = (const float*)d_in[6];
  const float* fw1 = (const float*)d_in[7];
  const float* fb1 = (const float*)d_in[8];
  const float* fw2 = (const float*)d_in[9];
  const float* fb2 = (const float*)d_in[10];
  float* out = (float*)d_out;

  const int B = in_sizes[0] / 784;  // 8192

  // ws (float units): Wm1[169*16*32 bf16] | Wm2 | Wm3 | Wbf | bf16 buffers
  const size_t nWm1 = (size_t)169 * 16 * 32 / 2;
  const size_t nWm2 = (size_t)36 * 32 * 160 / 2;
  const size_t nWm3 = (size_t)16 * 64 * 288 / 2;
  const size_t nWbf = (size_t)512 * 1024 / 2;
  unsigned short* Wm1 = (unsigned short*)d_ws;
  unsigned short* Wm2 = (unsigned short*)((float*)d_ws + nWm1);
  unsigned short* Wm3 = (unsigned short*)((float*)d_ws + nWm1 + nWm2);
  unsigned short* Wbf = (unsigned short*)((float*)d_ws + nWm1 + nWm2 + nWm3);
  unsigned short* hbase =
      (unsigned short*)((float*)d_ws + nWm1 + nWm2 + nWm3 + nWbf);
  const size_t ws_rem =
      ws_size - (nWm1 + nWm2 + nWm3 + nWbf) * sizeof(float);

  // per-batch-element bf16 shorts: xT 784 + h1 2704 + h2 1152 + h3 1024 + h4 512
  const size_t per_elem = (size_t)(784 + 2704 + 1152 + 1024 + 512) * 2;
  int Bc = B;
  while ((size_t)Bc * per_elem > ws_rem && Bc > 512) Bc >>= 1;
  const int nch = B / Bc;

  unsigned short* XT = hbase;
  unsigned short* H1 = XT + (size_t)784 * Bc;
  unsigned short* H2 = H1 + (size_t)1152 * 0 + (size_t)2704 * Bc;
  unsigned short* H3 = H2 + (size_t)1152 * Bc;
  unsigned short* H4 = H3 + (size_t)1024 * Bc;

  bool first = true;
  for (int ch = 0; ch < nch; ++ch) {
    const float* xc = x + (size_t)ch * Bc * 784;
    const int b0 = ch * Bc;
    const int nbt = Bc / 128;
    const int nbTr = (Bc / 32) * 25;

    // INIT: transpose this chunk + (first chunk only extends grid for weights)
    const int wallBlocks = first ? 533 : 1;  // tiny tail still re-runs: must be
    // deterministic per call; weight transforms are idempotent, so re-running
    // them every chunk is correct (and nch==1 for the real B=8192 case).
    k_init<<<dim3(nbTr + 533), 256, 0, stream>>>(xc, XT, Bc, nbTr, w1, w2, w3,
                                                 fw1, Wm1, Wm2, Wm3, Wbf);
    (void)wallBlocks;
    first = false;

    // LC1 per-position MFMA GEMM, 256-b tiles (overhead amortization)
    k_lcm<16, 9, 169, 784, 28, 13, 2, true, 256>
        <<<dim3(Bc / 256, 169), 256, 0, stream>>>(XT, Wm1, b1, H1, Bc);
    // LC2
    k_lcm<32, 144, 36, 169, 13, 6, 2, true>
        <<<dim3(nbt, 36), 256, 0, stream>>>(H1, Wm2, b2, H2, Bc);
    // LC3
    k_lcm<64, 288, 16, 36, 6, 4, 1, false>
        <<<dim3(nbt, 16), 256, 0, stream>>>(H2, Wm3, b3, H3, Bc);
    // FC1: h3 -> h4[512,Bc]  (64-b tiles: 512 blocks = 2/CU)
    k_fc1m<<<dim3(Bc / 64, 4), 256, 0, stream>>>(H3, Wbf, fb1, H4, Bc);
    // FC2: h4 -> out[b,10] f32  (8 waves/block)
    k_fc2<<<dim3(Bc / 64), dim3(64, 8), 0, stream>>>(H4, fw2, fb2, out, Bc,
                                                     b0);
  }
}